// Round 2
// baseline (32623.166 us; speedup 1.0000x reference)
//
#include <hip/hip_runtime.h>
#include <math.h>

// Problem constants
#define B    64
#define C    128
#define H    32
#define W    32
#define HW   1024          // H*W
#define OUTC 640           // 5*C
#define PS   37            // padded plane leading dim (halo 2 each side = 36, +1: odd stride -> conflict-free)
#define PLANE (PS*PS)      // 1369
#define NSKIP (B*C*HW)     // 8388608
#define NW    (8*C*C*9)    // 1179648 per weight array

// ws layout (in floats)
#define ALPHA_OFF 0                    // 40 floats of softmaxed alphas
#define S0_OFF    64
#define S1_OFF    (S0_OFF + NSKIP)
#define W3_OFF    (S1_OFF + NSKIP)     // alpha1-scaled conv3 weights
#define WD3_OFF   (W3_OFF + NW)        // alpha2-scaled dil3 weights
// total = 19,136,576 floats = 76.5 MB of workspace

// ---------------------------------------------------------------------------
// Prep: softmax(alphas) -> ws[0..40); scale w3 by a1, wd3 by a2 into ws.
// ---------------------------------------------------------------------------
__global__ __launch_bounds__(256) void prep_kernel(
    const float* __restrict__ alphas, const float* __restrict__ w3,
    const float* __restrict__ wd3, float* __restrict__ ws) {
  __shared__ float as[40];
  int tid = threadIdx.x;
  if (tid < 8) {
    float v[5];
    float m = -1e30f;
    for (int j = 0; j < 5; j++) { v[j] = alphas[tid * 5 + j]; m = fmaxf(m, v[j]); }
    float s = 0.f;
    for (int j = 0; j < 5; j++) { v[j] = __expf(v[j] - m); s += v[j]; }
    float inv = 1.f / s;
    for (int j = 0; j < 5; j++) as[tid * 5 + j] = v[j] * inv;
  }
  __syncthreads();
  if (blockIdx.x == 0 && tid < 40) ws[ALPHA_OFF + tid] = as[tid];
  int stride = gridDim.x * blockDim.x;
  for (int i = blockIdx.x * blockDim.x + tid; i < 2 * NW; i += stride) {
    if (i < NW) {
      int o = i / (C * C * 9);
      ws[W3_OFF + i] = as[o * 5 + 1] * w3[i];
    } else {
      int j = i - NW;
      int o = j / (C * C * 9);
      ws[WD3_OFF + j] = as[o * 5 + 2] * wd3[j];
    }
  }
}

// ---------------------------------------------------------------------------
// Preprocess 1x1 convs: s0 = in0 * wp0, s1 = in1 * wp1   (NCHW, OIHW)
// ---------------------------------------------------------------------------
__global__ __launch_bounds__(256) void pre_kernel(
    const float* __restrict__ in0, const float* __restrict__ in1,
    const float* __restrict__ wp0, const float* __restrict__ wp1,
    float* __restrict__ ws) {
  int which = blockIdx.z;
  const float* in = which ? in1 : in0;
  const float* wp = which ? wp1 : wp0;
  float* out = ws + (which ? S1_OFF : S0_OFF);
  int b = blockIdx.x;
  int cg = blockIdx.y;            // 8 groups of 16 co
  int t = threadIdx.x;
  int hw0 = t * 4;

  float4 acc[16];
  #pragma unroll
  for (int k = 0; k < 16; k++) acc[k] = make_float4(0.f, 0.f, 0.f, 0.f);

  const float* ip = in + b * (C * HW) + hw0;
  #pragma unroll 4
  for (int ci = 0; ci < C; ci++) {
    float4 x = *(const float4*)(ip + ci * HW);
    #pragma unroll
    for (int k = 0; k < 16; k++) {
      float wv = wp[(cg * 16 + k) * C + ci];   // uniform -> scalar load
      acc[k].x += wv * x.x; acc[k].y += wv * x.y;
      acc[k].z += wv * x.z; acc[k].w += wv * x.w;
    }
  }
  #pragma unroll
  for (int k = 0; k < 16; k++)
    *(float4*)(out + b * (C * HW) + (cg * 16 + k) * HW + hw0) = acc[k];
}

// ---------------------------------------------------------------------------
// Node kernel: s_new = mix(h0, edge o0) + mix(h1, edge o0+1).
// grid (64 b, 16 co-groups), block 256.  Each thread: 1x4 strip for 8 co.
//
// Pipelined version: LDS double-buffered plane pairs; halo zeroed ONCE
// (it never changes); interior = exactly one float4 per thread (4*tid).
// Per ci: issue 2 float4 prefetch loads (ci+1) -> compute ci (1152 FMA,
// hides the load latency) -> 8 ds_writes into other buffer -> 1 barrier.
// ---------------------------------------------------------------------------
__global__ __launch_bounds__(256, 4) void node_kernel(
    const float* __restrict__ h0, int h0_bs,
    const float* __restrict__ h1, int h1_bs,
    const float* __restrict__ ws, int o0,
    float* __restrict__ out) {
  __shared__ float pl[2][2][PLANE];   // [buf][input][plane]

  int b = blockIdx.x;
  int cog = blockIdx.y;           // 16 groups of 8 co
  int tid = threadIdx.x;
  int y = tid >> 3;               // 0..31
  int x0 = (tid & 7) * 4;         // 0..28

  // pool/identity alphas for the two edges (uniform scalar loads)
  float a0_0 = ws[ALPHA_OFF + o0 * 5 + 0];
  float a3_0 = ws[ALPHA_OFF + o0 * 5 + 3];
  float a4_0 = ws[ALPHA_OFF + o0 * 5 + 4];
  float a0_1 = ws[ALPHA_OFF + (o0 + 1) * 5 + 0];
  float a3_1 = ws[ALPHA_OFF + (o0 + 1) * 5 + 3];
  float a4_1 = ws[ALPHA_OFF + (o0 + 1) * 5 + 4];

  const float* w3_e0 = ws + W3_OFF  + o0 * (C * C * 9);
  const float* wd_e0 = ws + WD3_OFF + o0 * (C * C * 9);
  const float* w3_e1 = w3_e0 + (C * C * 9);
  const float* wd_e1 = wd_e0 + (C * C * 9);

  // interior element (y, x0) has linear offset y*32 + x0 == 4*tid
  const float* g0 = h0 + b * h0_bs + 4 * tid;
  const float* g1 = h1 + b * h1_bs + 4 * tid;

  // ---- zero both buffers once: halo cells stay zero for the whole kernel ----
  float* lbase = &pl[0][0][0];
  for (int j = tid; j < 4 * PLANE; j += 256) lbase[j] = 0.f;
  __syncthreads();

  int wo = (y + 2) * PS + (x0 + 2);

  { // prologue: stage ci=0 into buf 0
    float4 va = *(const float4*)g0;
    float4 vb = *(const float4*)g1;
    float* q0 = &pl[0][0][0];
    float* q1 = &pl[0][1][0];
    q0[wo] = va.x; q0[wo + 1] = va.y; q0[wo + 2] = va.z; q0[wo + 3] = va.w;
    q1[wo] = vb.x; q1[wo + 1] = vb.y; q1[wo + 2] = vb.z; q1[wo + 3] = vb.w;
  }
  __syncthreads();

  float acc[8][4];
  #pragma unroll
  for (int c = 0; c < 8; c++)
    #pragma unroll
    for (int k = 0; k < 4; k++) acc[c][k] = 0.f;

  int cur = 0;
  for (int ci = 0; ci < C; ci++) {
    // ---- prefetch ci+1 (latency hidden under this iteration's FMAs) ----
    float4 na = make_float4(0.f, 0.f, 0.f, 0.f);
    float4 nb = make_float4(0.f, 0.f, 0.f, 0.f);
    bool pf = (ci + 1 < C);
    if (pf) {
      na = *(const float4*)(g0 + (ci + 1) * HW);
      nb = *(const float4*)(g1 + (ci + 1) * HW);
    }
    __builtin_amdgcn_sched_barrier(0);   // pin the load issue at loop top

    const float* p0 = &pl[cur][0][0];
    const float* p1 = &pl[cur][1][0];

    // ---- neighborhoods into registers ----
    // A2/B2: rows y, y+2, y+4 (padded), cols x0..x0+7   (dilated conv)
    // A1t/A1b: rows y+1, y+3, cols x0+1..x0+6           (conv3 rows 0,2)
    // conv3 middle row (y+2) == A2[1] shifted by +1 -> reuse, saves 12 reads
    float A2[3][8], B2[3][8];
    float A1t[6], A1b[6], B1t[6], B1b[6];
    #pragma unroll
    for (int r = 0; r < 3; r++)
      #pragma unroll
      for (int c = 0; c < 8; c++) {
        A2[r][c] = p0[(y + 2 * r) * PS + x0 + c];
        B2[r][c] = p1[(y + 2 * r) * PS + x0 + c];
      }
    #pragma unroll
    for (int c = 0; c < 6; c++) {
      A1t[c] = p0[(y + 1) * PS + x0 + 1 + c];
      A1b[c] = p0[(y + 3) * PS + x0 + 1 + c];
      B1t[c] = p1[(y + 1) * PS + x0 + 1 + c];
      B1b[c] = p1[(y + 3) * PS + x0 + 1 + c];
    }

    // ---- identity / avg / max terms (uniform branch; 8 of 128 ci per block) ----
    int cidx = ci - cog * 8;
    if (cidx >= 0 && cidx < 8) {
      #pragma unroll
      for (int k = 0; k < 4; k++) {
        int x = x0 + k;
        bool ru = (y >= 1), rd = (y <= 30);
        bool cl = (x >= 1), cr = (x <= 30);
        // edge 0 (h0): window rows {A1t, A2[1]<<1, A1b}, cols k..k+2
        {
          float w00 = A1t[k], w01 = A1t[k + 1], w02 = A1t[k + 2];
          float w10 = A2[1][k + 1], w11 = A2[1][k + 2], w12 = A2[1][k + 3];
          float w20 = A1b[k], w21 = A1b[k + 1], w22 = A1b[k + 2];
          float s9 = w00 + w01 + w02 + w10 + w11 + w12 + w20 + w21 + w22;
          float cen = w11;
          float mx = cen;
          if (ru) { if (cl) mx = fmaxf(mx, w00); mx = fmaxf(mx, w01); if (cr) mx = fmaxf(mx, w02); }
          if (cl) mx = fmaxf(mx, w10);
          if (cr) mx = fmaxf(mx, w12);
          if (rd) { if (cl) mx = fmaxf(mx, w20); mx = fmaxf(mx, w21); if (cr) mx = fmaxf(mx, w22); }
          acc[cidx][k] += a0_0 * cen + a3_0 * (s9 * (1.f / 9.f)) + a4_0 * mx;
        }
        // edge 1 (h1)
        {
          float w00 = B1t[k], w01 = B1t[k + 1], w02 = B1t[k + 2];
          float w10 = B2[1][k + 1], w11 = B2[1][k + 2], w12 = B2[1][k + 3];
          float w20 = B1b[k], w21 = B1b[k + 1], w22 = B1b[k + 2];
          float s9 = w00 + w01 + w02 + w10 + w11 + w12 + w20 + w21 + w22;
          float cen = w11;
          float mx = cen;
          if (ru) { if (cl) mx = fmaxf(mx, w00); mx = fmaxf(mx, w01); if (cr) mx = fmaxf(mx, w02); }
          if (cl) mx = fmaxf(mx, w10);
          if (cr) mx = fmaxf(mx, w12);
          if (rd) { if (cl) mx = fmaxf(mx, w20); mx = fmaxf(mx, w21); if (cr) mx = fmaxf(mx, w22); }
          acc[cidx][k] += a0_1 * cen + a3_1 * (s9 * (1.f / 9.f)) + a4_1 * mx;
        }
      }
    }

    // ---- conv taps: 8 co x 9 taps x 4 pos x (2 convs x 2 inputs) = 1152 FMA ----
    #pragma unroll
    for (int c = 0; c < 8; c++) {
      int co = cog * 8 + c;
      const float* pw3_0 = w3_e0 + (co * C + ci) * 9;   // uniform -> s_load
      const float* pwd_0 = wd_e0 + (co * C + ci) * 9;
      const float* pw3_1 = w3_e1 + (co * C + ci) * 9;
      const float* pwd_1 = wd_e1 + (co * C + ci) * 9;
      #pragma unroll
      for (int t = 0; t < 9; t++) {
        int ky = t / 3, kx = t - ky * 3;
        float w3a = pw3_0[t], wda = pwd_0[t];
        float w3b = pw3_1[t], wdb = pwd_1[t];
        #pragma unroll
        for (int k = 0; k < 4; k++) {
          float a1v = (ky == 0) ? A1t[k + kx] : (ky == 1 ? A2[1][k + kx + 1] : A1b[k + kx]);
          float b1v = (ky == 0) ? B1t[k + kx] : (ky == 1 ? B2[1][k + kx + 1] : B1b[k + kx]);
          acc[c][k] += w3a * a1v;
          acc[c][k] += wda * A2[ky][k + 2 * kx];
          acc[c][k] += w3b * b1v;
          acc[c][k] += wdb * B2[ky][k + 2 * kx];
        }
      }
    }

    // ---- write prefetched ci+1 into the other buffer, then one barrier ----
    if (pf) {
      float* q0 = &pl[cur ^ 1][0][0];
      float* q1 = &pl[cur ^ 1][1][0];
      q0[wo] = na.x; q0[wo + 1] = na.y; q0[wo + 2] = na.z; q0[wo + 3] = na.w;
      q1[wo] = nb.x; q1[wo + 1] = nb.y; q1[wo + 2] = nb.z; q1[wo + 3] = nb.w;
    }
    __syncthreads();
    cur ^= 1;
  }

  // ---- write out (channel slot already folded into `out`) ----
  #pragma unroll
  for (int c = 0; c < 8; c++) {
    float* op = out + b * (OUTC * HW) + (cog * 8 + c) * HW + y * W + x0;
    *(float4*)op = make_float4(acc[c][0], acc[c][1], acc[c][2], acc[c][3]);
  }
}

// ---------------------------------------------------------------------------
// skip_input -> out channels [512,640) and second tuple output
// ---------------------------------------------------------------------------
__global__ __launch_bounds__(256) void skip_kernel(
    const float* __restrict__ skip, float* __restrict__ dout) {
  int i = blockIdx.x * 256 + threadIdx.x;     // over NSKIP/4 float4s
  if (i < NSKIP / 4) {
    float4 v = ((const float4*)skip)[i];
    int e = i * 4;
    int b = e >> 17;                 // / (C*HW)
    int rem = e & (C * HW - 1);
    *(float4*)(dout + b * (OUTC * HW) + 512 * HW + rem) = v;
    *(float4*)(dout + B * (OUTC * HW) + e) = v;
  }
}

// ---------------------------------------------------------------------------
extern "C" void kernel_launch(void* const* d_in, const int* in_sizes, int n_in,
                              void* d_out, int out_size, void* d_ws, size_t ws_size,
                              hipStream_t stream) {
  const float* input0 = (const float*)d_in[0];
  const float* input1 = (const float*)d_in[1];
  const float* skip   = (const float*)d_in[2];
  const float* wpre0  = (const float*)d_in[3];
  const float* wpre1  = (const float*)d_in[4];
  const float* wconv3 = (const float*)d_in[5];
  const float* wdil3  = (const float*)d_in[6];
  const float* alphas = (const float*)d_in[7];
  float* out = (float*)d_out;
  float* ws  = (float*)d_ws;   // needs ~76.5 MB

  prep_kernel<<<512, 256, 0, stream>>>(alphas, wconv3, wdil3, ws);
  pre_kernel<<<dim3(B, 8, 2), 256, 0, stream>>>(input0, input1, wpre0, wpre1, ws);

  const float* s0 = ws + S0_OFF;
  const float* s1 = ws + S1_OFF;
  const int wsb = C * HW;       // batch stride of ws-resident states
  const int ob  = OUTC * HW;    // batch stride of d_out-resident states

  // node0: s2 = mix(s0, e0) + mix(s1, e1)
  node_kernel<<<dim3(B, 16), 256, 0, stream>>>(s0, wsb, s1, wsb, ws, 0, out + 0 * C * HW);
  // node1: s3 = mix(s1, e2) + mix(s2, e3)
  node_kernel<<<dim3(B, 16), 256, 0, stream>>>(s1, wsb, out + 0 * C * HW, ob, ws, 2, out + 1 * C * HW);
  // node2: s4 = mix(s2, e4) + mix(s3, e5)
  node_kernel<<<dim3(B, 16), 256, 0, stream>>>(out + 0 * C * HW, ob, out + 1 * C * HW, ob, ws, 4, out + 2 * C * HW);
  // node3: s5 = mix(s3, e6) + mix(s4, e7)
  node_kernel<<<dim3(B, 16), 256, 0, stream>>>(out + 1 * C * HW, ob, out + 2 * C * HW, ob, ws, 6, out + 3 * C * HW);

  skip_kernel<<<(NSKIP / 4 + 255) / 256, 256, 0, stream>>>(skip, out);
}

// Round 4
// 16762.643 us; speedup vs baseline: 1.9462x; 1.9462x over previous
//
#include <hip/hip_runtime.h>
#include <math.h>

// Problem constants
#define B    64
#define C    128
#define H    32
#define W    32
#define HW   1024          // H*W
#define OUTC 640           // 5*C
#define PS   37            // padded plane leading dim (halo 2 each side = 36, +1: odd stride -> conflict-free)
#define PLANE (PS*PS)      // 1369
#define NSKIP (B*C*HW)     // 8388608
#define NW    (8*C*C*9)    // 1179648 per weight array

// ws layout (in floats)
#define ALPHA_OFF 0                    // 40 floats of softmaxed alphas
#define S0_OFF    64
#define S1_OFF    (S0_OFF + NSKIP)
#define W3_OFF    (S1_OFF + NSKIP)     // alpha1-scaled conv3 weights
#define WD3_OFF   (W3_OFF + NW)        // alpha2-scaled dil3 weights
// total = 19,136,576 floats = 76.5 MB of workspace

// ---------------------------------------------------------------------------
// Prep: softmax(alphas) -> ws[0..40); scale w3 by a1, wd3 by a2 into ws.
// ---------------------------------------------------------------------------
__global__ __launch_bounds__(256) void prep_kernel(
    const float* __restrict__ alphas, const float* __restrict__ w3,
    const float* __restrict__ wd3, float* __restrict__ ws) {
  __shared__ float as[40];
  int tid = threadIdx.x;
  if (tid < 8) {
    float v[5];
    float m = -1e30f;
    for (int j = 0; j < 5; j++) { v[j] = alphas[tid * 5 + j]; m = fmaxf(m, v[j]); }
    float s = 0.f;
    for (int j = 0; j < 5; j++) { v[j] = __expf(v[j] - m); s += v[j]; }
    float inv = 1.f / s;
    for (int j = 0; j < 5; j++) as[tid * 5 + j] = v[j] * inv;
  }
  __syncthreads();
  if (blockIdx.x == 0 && tid < 40) ws[ALPHA_OFF + tid] = as[tid];
  int stride = gridDim.x * blockDim.x;
  for (int i = blockIdx.x * blockDim.x + tid; i < 2 * NW; i += stride) {
    if (i < NW) {
      int o = i / (C * C * 9);
      ws[W3_OFF + i] = as[o * 5 + 1] * w3[i];
    } else {
      int j = i - NW;
      int o = j / (C * C * 9);
      ws[WD3_OFF + j] = as[o * 5 + 2] * wd3[j];
    }
  }
}

// ---------------------------------------------------------------------------
// Preprocess 1x1 convs: s0 = in0 * wp0, s1 = in1 * wp1   (NCHW, OIHW)
// ---------------------------------------------------------------------------
__global__ __launch_bounds__(256) void pre_kernel(
    const float* __restrict__ in0, const float* __restrict__ in1,
    const float* __restrict__ wp0, const float* __restrict__ wp1,
    float* __restrict__ ws) {
  int which = blockIdx.z;
  const float* in = which ? in1 : in0;
  const float* wp = which ? wp1 : wp0;
  float* out = ws + (which ? S1_OFF : S0_OFF);
  int b = blockIdx.x;
  int cg = blockIdx.y;            // 8 groups of 16 co
  int t = threadIdx.x;
  int hw0 = t * 4;

  float4 acc[16];
  #pragma unroll
  for (int k = 0; k < 16; k++) acc[k] = make_float4(0.f, 0.f, 0.f, 0.f);

  const float* ip = in + b * (C * HW) + hw0;
  #pragma unroll 4
  for (int ci = 0; ci < C; ci++) {
    float4 x = *(const float4*)(ip + ci * HW);
    #pragma unroll
    for (int k = 0; k < 16; k++) {
      float wv = wp[(cg * 16 + k) * C + ci];   // uniform -> scalar load
      acc[k].x += wv * x.x; acc[k].y += wv * x.y;
      acc[k].z += wv * x.z; acc[k].w += wv * x.w;
    }
  }
  #pragma unroll
  for (int k = 0; k < 16; k++)
    *(float4*)(out + b * (C * HW) + (cg * 16 + k) * HW + hw0) = acc[k];
}

// ---------------------------------------------------------------------------
// Node kernel: s_new = mix(h0, edge o0) + mix(h1, edge o0+1).
// grid (64 b, 16 co-groups), block 256.  Each thread: 1x4 strip for 8 co.
//
// Pipelined, 2 ci per barrier: LDS holds 2 double-buffered PAIRS of plane
// pairs ([buf][slot][input]); halo zeroed ONCE. Per iteration: prefetch 4
// float4 (ci+2, ci+3) -> compute ci, ci+1 (2304 FMA hides load latency)
// -> ds_write into other buffer -> ONE barrier per 2 channels.
// NOTE: plain __launch_bounds__(256) — no min-waves hint. A previous
// container's compiler turned the (256,4) hint into a 64-VGPR cap and
// spilled everything to scratch (18.7 GB FETCH/dispatch, 7.4x slower).
// ---------------------------------------------------------------------------
__global__ __launch_bounds__(256) void node_kernel(
    const float* __restrict__ h0, int h0_bs,
    const float* __restrict__ h1, int h1_bs,
    const float* __restrict__ ws, int o0,
    float* __restrict__ out) {
  __shared__ float pl[2][2][2][PLANE];   // [buf][ci-slot][input][plane]

  int b = blockIdx.x;
  int cog = blockIdx.y;           // 16 groups of 8 co
  int tid = threadIdx.x;
  int y = tid >> 3;               // 0..31
  int x0 = (tid & 7) * 4;         // 0..28

  // pool/identity alphas for the two edges (uniform scalar loads)
  float a0_0 = ws[ALPHA_OFF + o0 * 5 + 0];
  float a3_0 = ws[ALPHA_OFF + o0 * 5 + 3];
  float a4_0 = ws[ALPHA_OFF + o0 * 5 + 4];
  float a0_1 = ws[ALPHA_OFF + (o0 + 1) * 5 + 0];
  float a3_1 = ws[ALPHA_OFF + (o0 + 1) * 5 + 3];
  float a4_1 = ws[ALPHA_OFF + (o0 + 1) * 5 + 4];

  const float* w3_e0 = ws + W3_OFF  + o0 * (C * C * 9);
  const float* wd_e0 = ws + WD3_OFF + o0 * (C * C * 9);
  const float* w3_e1 = w3_e0 + (C * C * 9);
  const float* wd_e1 = wd_e0 + (C * C * 9);

  // interior element (y, x0) has linear offset y*32 + x0 == 4*tid
  const float* g0 = h0 + b * h0_bs + 4 * tid;
  const float* g1 = h1 + b * h1_bs + 4 * tid;

  // ---- zero all buffers once: halo cells stay zero for the whole kernel ----
  float* lbase = &pl[0][0][0][0];
  for (int j = tid; j < 8 * PLANE; j += 256) lbase[j] = 0.f;
  __syncthreads();

  int wo = (y + 2) * PS + (x0 + 2);

  { // prologue: stage ci=0,1 into buf 0
    float4 va0 = *(const float4*)g0;
    float4 vb0 = *(const float4*)g1;
    float4 va1 = *(const float4*)(g0 + HW);
    float4 vb1 = *(const float4*)(g1 + HW);
    float* q;
    q = &pl[0][0][0][0]; q[wo] = va0.x; q[wo+1] = va0.y; q[wo+2] = va0.z; q[wo+3] = va0.w;
    q = &pl[0][0][1][0]; q[wo] = vb0.x; q[wo+1] = vb0.y; q[wo+2] = vb0.z; q[wo+3] = vb0.w;
    q = &pl[0][1][0][0]; q[wo] = va1.x; q[wo+1] = va1.y; q[wo+2] = va1.z; q[wo+3] = va1.w;
    q = &pl[0][1][1][0]; q[wo] = vb1.x; q[wo+1] = vb1.y; q[wo+2] = vb1.z; q[wo+3] = vb1.w;
  }
  __syncthreads();

  float acc[8][4];
  #pragma unroll
  for (int c = 0; c < 8; c++)
    #pragma unroll
    for (int k = 0; k < 4; k++) acc[c][k] = 0.f;

  // ---- per-channel compute body (inlined twice per iteration) ----
  auto compute_ci = [&](int ci, const float* p0, const float* p1) {
    // A2/B2: rows y, y+2, y+4 (padded), cols x0..x0+7   (dilated conv)
    // A1t/A1b: rows y+1, y+3, cols x0+1..x0+6           (conv3 rows 0,2)
    // conv3 middle row (y+2) == A2[1] shifted by +1 -> reuse
    float A2[3][8], B2[3][8];
    float A1t[6], A1b[6], B1t[6], B1b[6];
    #pragma unroll
    for (int r = 0; r < 3; r++)
      #pragma unroll
      for (int c = 0; c < 8; c++) {
        A2[r][c] = p0[(y + 2 * r) * PS + x0 + c];
        B2[r][c] = p1[(y + 2 * r) * PS + x0 + c];
      }
    #pragma unroll
    for (int c = 0; c < 6; c++) {
      A1t[c] = p0[(y + 1) * PS + x0 + 1 + c];
      A1b[c] = p0[(y + 3) * PS + x0 + 1 + c];
      B1t[c] = p1[(y + 1) * PS + x0 + 1 + c];
      B1b[c] = p1[(y + 3) * PS + x0 + 1 + c];
    }

    // identity / avg / max terms (uniform branch; 8 of 128 ci per block)
    int cidx = ci - cog * 8;
    if (cidx >= 0 && cidx < 8) {
      #pragma unroll
      for (int k = 0; k < 4; k++) {
        int x = x0 + k;
        bool ru = (y >= 1), rd = (y <= 30);
        bool cl = (x >= 1), cr = (x <= 30);
        // edge 0 (h0): window rows {A1t, A2[1]<<1, A1b}, cols k..k+2
        {
          float w00 = A1t[k], w01 = A1t[k + 1], w02 = A1t[k + 2];
          float w10 = A2[1][k + 1], w11 = A2[1][k + 2], w12 = A2[1][k + 3];
          float w20 = A1b[k], w21 = A1b[k + 1], w22 = A1b[k + 2];
          float s9 = w00 + w01 + w02 + w10 + w11 + w12 + w20 + w21 + w22;
          float cen = w11;
          float mx = cen;
          if (ru) { if (cl) mx = fmaxf(mx, w00); mx = fmaxf(mx, w01); if (cr) mx = fmaxf(mx, w02); }
          if (cl) mx = fmaxf(mx, w10);
          if (cr) mx = fmaxf(mx, w12);
          if (rd) { if (cl) mx = fmaxf(mx, w20); mx = fmaxf(mx, w21); if (cr) mx = fmaxf(mx, w22); }
          acc[cidx][k] += a0_0 * cen + a3_0 * (s9 * (1.f / 9.f)) + a4_0 * mx;
        }
        // edge 1 (h1)
        {
          float w00 = B1t[k], w01 = B1t[k + 1], w02 = B1t[k + 2];
          float w10 = B2[1][k + 1], w11 = B2[1][k + 2], w12 = B2[1][k + 3];
          float w20 = B1b[k], w21 = B1b[k + 1], w22 = B1b[k + 2];
          float s9 = w00 + w01 + w02 + w10 + w11 + w12 + w20 + w21 + w22;
          float cen = w11;
          float mx = cen;
          if (ru) { if (cl) mx = fmaxf(mx, w00); mx = fmaxf(mx, w01); if (cr) mx = fmaxf(mx, w02); }
          if (cl) mx = fmaxf(mx, w10);
          if (cr) mx = fmaxf(mx, w12);
          if (rd) { if (cl) mx = fmaxf(mx, w20); mx = fmaxf(mx, w21); if (cr) mx = fmaxf(mx, w22); }
          acc[cidx][k] += a0_1 * cen + a3_1 * (s9 * (1.f / 9.f)) + a4_1 * mx;
        }
      }
    }

    // conv taps: 8 co x 9 taps x 4 pos x (2 convs x 2 inputs) = 1152 FMA
    #pragma unroll
    for (int c = 0; c < 8; c++) {
      int co = cog * 8 + c;
      const float* pw3_0 = w3_e0 + (co * C + ci) * 9;   // uniform -> s_load
      const float* pwd_0 = wd_e0 + (co * C + ci) * 9;
      const float* pw3_1 = w3_e1 + (co * C + ci) * 9;
      const float* pwd_1 = wd_e1 + (co * C + ci) * 9;
      #pragma unroll
      for (int t = 0; t < 9; t++) {
        int ky = t / 3, kx = t - ky * 3;
        float w3a = pw3_0[t], wda = pwd_0[t];
        float w3b = pw3_1[t], wdb = pwd_1[t];
        #pragma unroll
        for (int k = 0; k < 4; k++) {
          float a1v = (ky == 0) ? A1t[k + kx] : (ky == 1 ? A2[1][k + kx + 1] : A1b[k + kx]);
          float b1v = (ky == 0) ? B1t[k + kx] : (ky == 1 ? B2[1][k + kx + 1] : B1b[k + kx]);
          acc[c][k] += w3a * a1v;
          acc[c][k] += wda * A2[ky][k + 2 * kx];
          acc[c][k] += w3b * b1v;
          acc[c][k] += wdb * B2[ky][k + 2 * kx];
        }
      }
    }
  };

  int cur = 0;
  for (int t2 = 0; t2 < C / 2; t2++) {
    // ---- prefetch ci+2, ci+3 (latency hidden under 2304 FMAs) ----
    float4 na0 = make_float4(0.f, 0.f, 0.f, 0.f);
    float4 nb0 = make_float4(0.f, 0.f, 0.f, 0.f);
    float4 na1 = make_float4(0.f, 0.f, 0.f, 0.f);
    float4 nb1 = make_float4(0.f, 0.f, 0.f, 0.f);
    bool pf = (t2 + 1 < C / 2);
    if (pf) {
      na0 = *(const float4*)(g0 + (2 * t2 + 2) * HW);
      nb0 = *(const float4*)(g1 + (2 * t2 + 2) * HW);
      na1 = *(const float4*)(g0 + (2 * t2 + 3) * HW);
      nb1 = *(const float4*)(g1 + (2 * t2 + 3) * HW);
    }
    __builtin_amdgcn_sched_barrier(0);   // pin the load issue at loop top

    compute_ci(2 * t2,     &pl[cur][0][0][0], &pl[cur][0][1][0]);
    compute_ci(2 * t2 + 1, &pl[cur][1][0][0], &pl[cur][1][1][0]);

    // ---- write prefetched channels into the other buffer, then one barrier ----
    if (pf) {
      float* q;
      q = &pl[cur ^ 1][0][0][0]; q[wo] = na0.x; q[wo+1] = na0.y; q[wo+2] = na0.z; q[wo+3] = na0.w;
      q = &pl[cur ^ 1][0][1][0]; q[wo] = nb0.x; q[wo+1] = nb0.y; q[wo+2] = nb0.z; q[wo+3] = nb0.w;
      q = &pl[cur ^ 1][1][0][0]; q[wo] = na1.x; q[wo+1] = na1.y; q[wo+2] = na1.z; q[wo+3] = na1.w;
      q = &pl[cur ^ 1][1][1][0]; q[wo] = nb1.x; q[wo+1] = nb1.y; q[wo+2] = nb1.z; q[wo+3] = nb1.w;
    }
    __syncthreads();
    cur ^= 1;
  }

  // ---- write out (channel slot already folded into `out`) ----
  #pragma unroll
  for (int c = 0; c < 8; c++) {
    float* op = out + b * (OUTC * HW) + (cog * 8 + c) * HW + y * W + x0;
    *(float4*)op = make_float4(acc[c][0], acc[c][1], acc[c][2], acc[c][3]);
  }
}

// ---------------------------------------------------------------------------
// skip_input -> out channels [512,640) and second tuple output
// ---------------------------------------------------------------------------
__global__ __launch_bounds__(256) void skip_kernel(
    const float* __restrict__ skip, float* __restrict__ dout) {
  int i = blockIdx.x * 256 + threadIdx.x;     // over NSKIP/4 float4s
  if (i < NSKIP / 4) {
    float4 v = ((const float4*)skip)[i];
    int e = i * 4;
    int b = e >> 17;                 // / (C*HW)
    int rem = e & (C * HW - 1);
    *(float4*)(dout + b * (OUTC * HW) + 512 * HW + rem) = v;
    *(float4*)(dout + B * (OUTC * HW) + e) = v;
  }
}

// ---------------------------------------------------------------------------
extern "C" void kernel_launch(void* const* d_in, const int* in_sizes, int n_in,
                              void* d_out, int out_size, void* d_ws, size_t ws_size,
                              hipStream_t stream) {
  const float* input0 = (const float*)d_in[0];
  const float* input1 = (const float*)d_in[1];
  const float* skip   = (const float*)d_in[2];
  const float* wpre0  = (const float*)d_in[3];
  const float* wpre1  = (const float*)d_in[4];
  const float* wconv3 = (const float*)d_in[5];
  const float* wdil3  = (const float*)d_in[6];
  const float* alphas = (const float*)d_in[7];
  float* out = (float*)d_out;
  float* ws  = (float*)d_ws;   // needs ~76.5 MB

  prep_kernel<<<512, 256, 0, stream>>>(alphas, wconv3, wdil3, ws);
  pre_kernel<<<dim3(B, 8, 2), 256, 0, stream>>>(input0, input1, wpre0, wpre1, ws);

  const float* s0 = ws + S0_OFF;
  const float* s1 = ws + S1_OFF;
  const int wsb = C * HW;       // batch stride of ws-resident states
  const int ob  = OUTC * HW;    // batch stride of d_out-resident states

  // node0: s2 = mix(s0, e0) + mix(s1, e1)
  node_kernel<<<dim3(B, 16), 256, 0, stream>>>(s0, wsb, s1, wsb, ws, 0, out + 0 * C * HW);
  // node1: s3 = mix(s1, e2) + mix(s2, e3)
  node_kernel<<<dim3(B, 16), 256, 0, stream>>>(s1, wsb, out + 0 * C * HW, ob, ws, 2, out + 1 * C * HW);
  // node2: s4 = mix(s2, e4) + mix(s3, e5)
  node_kernel<<<dim3(B, 16), 256, 0, stream>>>(out + 0 * C * HW, ob, out + 1 * C * HW, ob, ws, 4, out + 2 * C * HW);
  // node3: s5 = mix(s3, e6) + mix(s4, e7)
  node_kernel<<<dim3(B, 16), 256, 0, stream>>>(out + 1 * C * HW, ob, out + 2 * C * HW, ob, ws, 6, out + 3 * C * HW);

  skip_kernel<<<(NSKIP / 4 + 255) / 256, 256, 0, stream>>>(skip, out);
}

// Round 5
// 11268.542 us; speedup vs baseline: 2.8951x; 1.4876x over previous
//
#include <hip/hip_runtime.h>
#include <math.h>

// Problem constants
#define B    64
#define C    128
#define H    32
#define W    32
#define HW   1024          // H*W
#define OUTC 640           // 5*C
#define NSKIP (B*C*HW)     // 8388608
#define NW    (8*C*C*9)    // 1179648 per weight array

// Wave-private band geometry: each wave owns 8 output rows + 2-row halo each
// side; 32 cols + 2-col halo each side, padded to 40 floats so every row is
// 16B-aligned (ds_read_b128-able).
#define BRS   40
#define BROWS 12
#define BPLANE (BROWS*BRS)   // 480 floats

// ws layout (in floats)
#define ALPHA_OFF 0                    // 40 floats of softmaxed alphas
#define S0_OFF    64
#define S1_OFF    (S0_OFF + NSKIP)
#define W3_OFF    (S1_OFF + NSKIP)     // alpha1-scaled conv3 weights
#define WD3_OFF   (W3_OFF + NW)        // alpha2-scaled dil3 weights
// total = 19,136,576 floats = 76.5 MB of workspace

// ---------------------------------------------------------------------------
// Prep: softmax(alphas) -> ws[0..40); scale w3 by a1, wd3 by a2 into ws.
// ---------------------------------------------------------------------------
__global__ __launch_bounds__(256) void prep_kernel(
    const float* __restrict__ alphas, const float* __restrict__ w3,
    const float* __restrict__ wd3, float* __restrict__ ws) {
  __shared__ float as[40];
  int tid = threadIdx.x;
  if (tid < 8) {
    float v[5];
    float m = -1e30f;
    for (int j = 0; j < 5; j++) { v[j] = alphas[tid * 5 + j]; m = fmaxf(m, v[j]); }
    float s = 0.f;
    for (int j = 0; j < 5; j++) { v[j] = __expf(v[j] - m); s += v[j]; }
    float inv = 1.f / s;
    for (int j = 0; j < 5; j++) as[tid * 5 + j] = v[j] * inv;
  }
  __syncthreads();
  if (blockIdx.x == 0 && tid < 40) ws[ALPHA_OFF + tid] = as[tid];
  int stride = gridDim.x * blockDim.x;
  for (int i = blockIdx.x * blockDim.x + tid; i < 2 * NW; i += stride) {
    if (i < NW) {
      int o = i / (C * C * 9);
      ws[W3_OFF + i] = as[o * 5 + 1] * w3[i];
    } else {
      int j = i - NW;
      int o = j / (C * C * 9);
      ws[WD3_OFF + j] = as[o * 5 + 2] * wd3[j];
    }
  }
}

// ---------------------------------------------------------------------------
// Preprocess 1x1 convs: s0 = in0 * wp0, s1 = in1 * wp1   (NCHW, OIHW)
// ---------------------------------------------------------------------------
__global__ __launch_bounds__(256) void pre_kernel(
    const float* __restrict__ in0, const float* __restrict__ in1,
    const float* __restrict__ wp0, const float* __restrict__ wp1,
    float* __restrict__ ws) {
  int which = blockIdx.z;
  const float* in = which ? in1 : in0;
  const float* wp = which ? wp1 : wp0;
  float* out = ws + (which ? S1_OFF : S0_OFF);
  int b = blockIdx.x;
  int cg = blockIdx.y;            // 8 groups of 16 co
  int t = threadIdx.x;
  int hw0 = t * 4;

  float4 acc[16];
  #pragma unroll
  for (int k = 0; k < 16; k++) acc[k] = make_float4(0.f, 0.f, 0.f, 0.f);

  const float* ip = in + b * (C * HW) + hw0;
  #pragma unroll 4
  for (int ci = 0; ci < C; ci++) {
    float4 x = *(const float4*)(ip + ci * HW);
    #pragma unroll
    for (int k = 0; k < 16; k++) {
      float wv = wp[(cg * 16 + k) * C + ci];   // uniform -> scalar load
      acc[k].x += wv * x.x; acc[k].y += wv * x.y;
      acc[k].z += wv * x.z; acc[k].w += wv * x.w;
    }
  }
  #pragma unroll
  for (int k = 0; k < 16; k++)
    *(float4*)(out + b * (C * HW) + (cg * 16 + k) * HW + hw0) = acc[k];
}

// ---------------------------------------------------------------------------
// Node kernel: s_new = mix(h0, edge o0) + mix(h1, edge o0+1).
// grid (64 b, 16 co-groups), block 256.  Each thread: 1x4 strip for 8 co.
//
// BARRIER-FREE main loop: each wave owns output rows 8w..8w+7 and stages its
// own 12-row x 40-col band (incl. 2-row halos it loads redundantly from
// global) into wave-private LDS.  No inter-wave LDS sharing -> zero
// __syncthreads in the loop; waves self-pace, per-wave lgkmcnt waits hide
// under other waves' FMAs.  Rows are 16B-aligned -> 20 ds_read_b128/ci
// (vs 72 ds_read_b32).  Tap loop is row-streamed: 5 row blocks, one 16-float
// row pair live at a time, keeping VGPR <= 128 (the occupancy cliff: Round-4's
// 148-VGPR kernel halved residency and ran 4x slower).
// NOTE: plain __launch_bounds__(256) — a previous container's compiler turned
// a (256,4) hint into a 64-VGPR cap and spilled everything to scratch.
// ---------------------------------------------------------------------------
__global__ __launch_bounds__(256) void node_kernel(
    const float* __restrict__ h0, int h0_bs,
    const float* __restrict__ h1, int h1_bs,
    const float* __restrict__ ws, int o0,
    float* __restrict__ out) {
  __shared__ float band[4][2][2][BPLANE];   // [wave][buf][input][plane] = 30720 B

  int b = blockIdx.x;
  int cog = blockIdx.y;           // 16 groups of 8 co
  int tid = threadIdx.x;
  int wv = tid >> 6;              // wave 0..3: owns rows 8wv..8wv+7
  int l  = tid & 63;
  int ly = l >> 3;                // 0..7 row within band
  int x0 = (l & 7) * 4;           // 0..28
  int y  = wv * 8 + ly;           // global output row

  // pool/identity alphas for the two edges (uniform scalar loads)
  float a0_0 = ws[ALPHA_OFF + o0 * 5 + 0];
  float a3_0 = ws[ALPHA_OFF + o0 * 5 + 3];
  float a4_0 = ws[ALPHA_OFF + o0 * 5 + 4];
  float a0_1 = ws[ALPHA_OFF + (o0 + 1) * 5 + 0];
  float a3_1 = ws[ALPHA_OFF + (o0 + 1) * 5 + 3];
  float a4_1 = ws[ALPHA_OFF + (o0 + 1) * 5 + 4];

  const float* w3_e0 = ws + W3_OFF  + o0 * (C * C * 9);
  const float* wd_e0 = ws + WD3_OFF + o0 * (C * C * 9);
  const float* w3_e1 = w3_e0 + (C * C * 9);
  const float* wd_e1 = wd_e0 + (C * C * 9);

  // interior global pointers (this thread's own float4 per plane)
  const float* gi0 = h0 + b * h0_bs + y * W + x0;
  const float* gi1 = h1 + b * h1_bs + y * W + x0;

  // halo assignment: lanes 0..15 load the 2 rows above the band,
  // lanes 16..31 the 2 rows below.  8 lanes per row (one float4 each).
  bool top  = (l < 16);
  int  hp   = (l >> 3) & 1;                       // row within halo pair
  int  hrow = top ? (wv * 8 - 2 + hp) : (wv * 8 + 8 + hp);
  bool hval = (l < 32) && (top ? (wv > 0) : (wv < 3));
  int  hcol = (l & 7) * 4;
  int  hrc  = hrow < 0 ? 0 : (hrow > 31 ? 31 : hrow);   // addr-safe clamp
  const float* gh0 = h0 + b * h0_bs + hrc * W + hcol;
  const float* gh1 = h1 + b * h1_bs + hrc * W + hcol;
  int hwo = (top ? hp : 10 + hp) * BRS + hcol + 2;
  int wo  = (ly + 2) * BRS + x0 + 2;

  // ---- zero all bands once (halos at grid edges + col pads stay zero) ----
  {
    float* zb = &band[0][0][0][0];
    for (int j = tid; j < 4 * 2 * 2 * BPLANE; j += 256) zb[j] = 0.f;
  }
  __syncthreads();   // the ONLY barrier in this kernel

  float* b00 = &band[wv][0][0][0];
  float* b01 = &band[wv][0][1][0];
  float* b10 = &band[wv][1][0][0];
  float* b11 = &band[wv][1][1][0];

  { // prologue: stage ci=0 into buf 0 (own wave's band only)
    float4 ia = *(const float4*)gi0;
    float4 ib = *(const float4*)gi1;
    b00[wo] = ia.x; b00[wo+1] = ia.y; b00[wo+2] = ia.z; b00[wo+3] = ia.w;
    b01[wo] = ib.x; b01[wo+1] = ib.y; b01[wo+2] = ib.z; b01[wo+3] = ib.w;
    if (hval) {
      float4 ha = *(const float4*)gh0;
      float4 hb = *(const float4*)gh1;
      b00[hwo] = ha.x; b00[hwo+1] = ha.y; b00[hwo+2] = ha.z; b00[hwo+3] = ha.w;
      b01[hwo] = hb.x; b01[hwo+1] = hb.y; b01[hwo+2] = hb.z; b01[hwo+3] = hb.w;
    }
  }

  float acc[8][4];
  #pragma unroll
  for (int c = 0; c < 8; c++)
    #pragma unroll
    for (int k = 0; k < 4; k++) acc[c][k] = 0.f;

  bool ru = (y >= 1), rd = (y <= 30);

  // ---- per-channel compute, row-streamed (5 row blocks) ----
  // band row ly+r holds actual input row y+r-2; band col j holds x=j-2.
  // dilated taps (ky): rows r=2ky, cols Ra[k+2kx].  conv3 (ky): rows r=ky+1,
  // cols Ra[k+kx+1].  pool/identity: rows r=1..3, cols Ra[k+1..k+3].
  auto compute_ci = [&](int ci, const float* p0, const float* p1) {
    int cidx = ci - cog * 8;
    bool dopool = (cidx >= 0) & (cidx < 8);
    float cenA[4], cenB[4], s9A[4], s9B[4], mxA[4], mxB[4];
    int wq = (cog * 8 * C + ci) * 9;   // weight index for c=0

    // --- r=0: dilated ky=0 ---
    {
      const float* rp0 = p0 + ly * BRS + x0;
      const float* rp1 = p1 + ly * BRS + x0;
      float Ra[8], Rb[8];
      *(float4*)&Ra[0] = *(const float4*)(rp0);
      *(float4*)&Ra[4] = *(const float4*)(rp0 + 4);
      *(float4*)&Rb[0] = *(const float4*)(rp1);
      *(float4*)&Rb[4] = *(const float4*)(rp1 + 4);
      #pragma unroll
      for (int c = 0; c < 8; c++) {
        int wi = wq + c * (C * 9);
        #pragma unroll
        for (int kx = 0; kx < 3; kx++) {
          float wa = wd_e0[wi + kx], wb = wd_e1[wi + kx];
          #pragma unroll
          for (int k = 0; k < 4; k++) {
            acc[c][k] += wa * Ra[k + 2 * kx];
            acc[c][k] += wb * Rb[k + 2 * kx];
          }
        }
      }
    }
    // --- r=1: conv3 ky=0, pool top row ---
    {
      const float* rp0 = p0 + (ly + 1) * BRS + x0;
      const float* rp1 = p1 + (ly + 1) * BRS + x0;
      float Ra[8], Rb[8];
      *(float4*)&Ra[0] = *(const float4*)(rp0);
      *(float4*)&Ra[4] = *(const float4*)(rp0 + 4);
      *(float4*)&Rb[0] = *(const float4*)(rp1);
      *(float4*)&Rb[4] = *(const float4*)(rp1 + 4);
      #pragma unroll
      for (int c = 0; c < 8; c++) {
        int wi = wq + c * (C * 9);
        #pragma unroll
        for (int kx = 0; kx < 3; kx++) {
          float wa = w3_e0[wi + kx], wb = w3_e1[wi + kx];
          #pragma unroll
          for (int k = 0; k < 4; k++) {
            acc[c][k] += wa * Ra[k + kx + 1];
            acc[c][k] += wb * Rb[k + kx + 1];
          }
        }
      }
      if (dopool) {
        #pragma unroll
        for (int k = 0; k < 4; k++) {
          s9A[k] = Ra[k+1] + Ra[k+2] + Ra[k+3];
          s9B[k] = Rb[k+1] + Rb[k+2] + Rb[k+3];
          float ma = -1e30f, mb = -1e30f;
          if (ru) {
            if (x0 + k >= 1)  { ma = fmaxf(ma, Ra[k+1]); mb = fmaxf(mb, Rb[k+1]); }
            ma = fmaxf(ma, Ra[k+2]); mb = fmaxf(mb, Rb[k+2]);
            if (x0 + k <= 30) { ma = fmaxf(ma, Ra[k+3]); mb = fmaxf(mb, Rb[k+3]); }
          }
          mxA[k] = ma; mxB[k] = mb;
        }
      }
    }
    // --- r=2: dilated ky=1, conv3 ky=1, pool mid row + identity center ---
    {
      const float* rp0 = p0 + (ly + 2) * BRS + x0;
      const float* rp1 = p1 + (ly + 2) * BRS + x0;
      float Ra[8], Rb[8];
      *(float4*)&Ra[0] = *(const float4*)(rp0);
      *(float4*)&Ra[4] = *(const float4*)(rp0 + 4);
      *(float4*)&Rb[0] = *(const float4*)(rp1);
      *(float4*)&Rb[4] = *(const float4*)(rp1 + 4);
      #pragma unroll
      for (int c = 0; c < 8; c++) {
        int wi = wq + c * (C * 9);
        #pragma unroll
        for (int kx = 0; kx < 3; kx++) {
          float wa = wd_e0[wi + 3 + kx], wb = wd_e1[wi + 3 + kx];
          #pragma unroll
          for (int k = 0; k < 4; k++) {
            acc[c][k] += wa * Ra[k + 2 * kx];
            acc[c][k] += wb * Rb[k + 2 * kx];
          }
        }
        #pragma unroll
        for (int kx = 0; kx < 3; kx++) {
          float wa = w3_e0[wi + 3 + kx], wb = w3_e1[wi + 3 + kx];
          #pragma unroll
          for (int k = 0; k < 4; k++) {
            acc[c][k] += wa * Ra[k + kx + 1];
            acc[c][k] += wb * Rb[k + kx + 1];
          }
        }
      }
      if (dopool) {
        #pragma unroll
        for (int k = 0; k < 4; k++) {
          s9A[k] += Ra[k+1] + Ra[k+2] + Ra[k+3];
          s9B[k] += Rb[k+1] + Rb[k+2] + Rb[k+3];
          cenA[k] = Ra[k+2]; cenB[k] = Rb[k+2];
          float ma = mxA[k], mb = mxB[k];
          if (x0 + k >= 1)  { ma = fmaxf(ma, Ra[k+1]); mb = fmaxf(mb, Rb[k+1]); }
          ma = fmaxf(ma, Ra[k+2]); mb = fmaxf(mb, Rb[k+2]);
          if (x0 + k <= 30) { ma = fmaxf(ma, Ra[k+3]); mb = fmaxf(mb, Rb[k+3]); }
          mxA[k] = ma; mxB[k] = mb;
        }
      }
    }
    // --- r=3: conv3 ky=2, pool bottom row ---
    {
      const float* rp0 = p0 + (ly + 3) * BRS + x0;
      const float* rp1 = p1 + (ly + 3) * BRS + x0;
      float Ra[8], Rb[8];
      *(float4*)&Ra[0] = *(const float4*)(rp0);
      *(float4*)&Ra[4] = *(const float4*)(rp0 + 4);
      *(float4*)&Rb[0] = *(const float4*)(rp1);
      *(float4*)&Rb[4] = *(const float4*)(rp1 + 4);
      #pragma unroll
      for (int c = 0; c < 8; c++) {
        int wi = wq + c * (C * 9);
        #pragma unroll
        for (int kx = 0; kx < 3; kx++) {
          float wa = w3_e0[wi + 6 + kx], wb = w3_e1[wi + 6 + kx];
          #pragma unroll
          for (int k = 0; k < 4; k++) {
            acc[c][k] += wa * Ra[k + kx + 1];
            acc[c][k] += wb * Rb[k + kx + 1];
          }
        }
      }
      if (dopool) {
        #pragma unroll
        for (int k = 0; k < 4; k++) {
          s9A[k] += Ra[k+1] + Ra[k+2] + Ra[k+3];
          s9B[k] += Rb[k+1] + Rb[k+2] + Rb[k+3];
          float ma = mxA[k], mb = mxB[k];
          if (rd) {
            if (x0 + k >= 1)  { ma = fmaxf(ma, Ra[k+1]); mb = fmaxf(mb, Rb[k+1]); }
            ma = fmaxf(ma, Ra[k+2]); mb = fmaxf(mb, Rb[k+2]);
            if (x0 + k <= 30) { ma = fmaxf(ma, Ra[k+3]); mb = fmaxf(mb, Rb[k+3]); }
          }
          mxA[k] = ma; mxB[k] = mb;
        }
      }
    }
    // --- r=4: dilated ky=2 ---
    {
      const float* rp0 = p0 + (ly + 4) * BRS + x0;
      const float* rp1 = p1 + (ly + 4) * BRS + x0;
      float Ra[8], Rb[8];
      *(float4*)&Ra[0] = *(const float4*)(rp0);
      *(float4*)&Ra[4] = *(const float4*)(rp0 + 4);
      *(float4*)&Rb[0] = *(const float4*)(rp1);
      *(float4*)&Rb[4] = *(const float4*)(rp1 + 4);
      #pragma unroll
      for (int c = 0; c < 8; c++) {
        int wi = wq + c * (C * 9);
        #pragma unroll
        for (int kx = 0; kx < 3; kx++) {
          float wa = wd_e0[wi + 6 + kx], wb = wd_e1[wi + 6 + kx];
          #pragma unroll
          for (int k = 0; k < 4; k++) {
            acc[c][k] += wa * Ra[k + 2 * kx];
            acc[c][k] += wb * Rb[k + 2 * kx];
          }
        }
      }
    }
    // --- identity / avg / max contribution ---
    if (dopool) {
      #pragma unroll
      for (int k = 0; k < 4; k++) {
        acc[cidx][k] += a0_0 * cenA[k] + a3_0 * (s9A[k] * (1.f / 9.f)) + a4_0 * mxA[k];
        acc[cidx][k] += a0_1 * cenB[k] + a3_1 * (s9B[k] * (1.f / 9.f)) + a4_1 * mxB[k];
      }
    }
  };

  // one pipeline step: prefetch ci+1 -> compute ci from read-buf -> stage
  // prefetched plane into write-buf.  No barrier: all LDS deps are
  // within-wave, ordered by the compiler's lgkmcnt waits.
  auto step = [&](int ci, const float* r0, const float* r1, float* w0, float* w1) {
    float4 ia = make_float4(0.f, 0.f, 0.f, 0.f), ib = ia, ha = ia, hb = ia;
    bool pf = (ci + 1 < C);
    if (pf) {
      ia = *(const float4*)(gi0 + (ci + 1) * HW);
      ib = *(const float4*)(gi1 + (ci + 1) * HW);
      if (hval) {
        ha = *(const float4*)(gh0 + (ci + 1) * HW);
        hb = *(const float4*)(gh1 + (ci + 1) * HW);
      }
    }
    __builtin_amdgcn_sched_barrier(0);   // pin load issue at step top
    compute_ci(ci, r0, r1);
    if (pf) {
      w0[wo] = ia.x; w0[wo+1] = ia.y; w0[wo+2] = ia.z; w0[wo+3] = ia.w;
      w1[wo] = ib.x; w1[wo+1] = ib.y; w1[wo+2] = ib.z; w1[wo+3] = ib.w;
      if (hval) {
        w0[hwo] = ha.x; w0[hwo+1] = ha.y; w0[hwo+2] = ha.z; w0[hwo+3] = ha.w;
        w1[hwo] = hb.x; w1[hwo+1] = hb.y; w1[hwo+2] = hb.z; w1[hwo+3] = hb.w;
      }
    }
  };

  for (int ci = 0; ci < C; ci += 2) {   // static double-buffer alternation
    step(ci,     b00, b01, b10, b11);
    step(ci + 1, b10, b11, b00, b01);
  }

  // ---- write out (channel slot already folded into `out`) ----
  #pragma unroll
  for (int c = 0; c < 8; c++) {
    float* op = out + b * (OUTC * HW) + (cog * 8 + c) * HW + y * W + x0;
    *(float4*)op = make_float4(acc[c][0], acc[c][1], acc[c][2], acc[c][3]);
  }
}

// ---------------------------------------------------------------------------
// skip_input -> out channels [512,640) and second tuple output
// ---------------------------------------------------------------------------
__global__ __launch_bounds__(256) void skip_kernel(
    const float* __restrict__ skip, float* __restrict__ dout) {
  int i = blockIdx.x * 256 + threadIdx.x;     // over NSKIP/4 float4s
  if (i < NSKIP / 4) {
    float4 v = ((const float4*)skip)[i];
    int e = i * 4;
    int b = e >> 17;                 // / (C*HW)
    int rem = e & (C * HW - 1);
    *(float4*)(dout + b * (OUTC * HW) + 512 * HW + rem) = v;
    *(float4*)(dout + B * (OUTC * HW) + e) = v;
  }
}

// ---------------------------------------------------------------------------
extern "C" void kernel_launch(void* const* d_in, const int* in_sizes, int n_in,
                              void* d_out, int out_size, void* d_ws, size_t ws_size,
                              hipStream_t stream) {
  const float* input0 = (const float*)d_in[0];
  const float* input1 = (const float*)d_in[1];
  const float* skip   = (const float*)d_in[2];
  const float* wpre0  = (const float*)d_in[3];
  const float* wpre1  = (const float*)d_in[4];
  const float* wconv3 = (const float*)d_in[5];
  const float* wdil3  = (const float*)d_in[6];
  const float* alphas = (const float*)d_in[7];
  float* out = (float*)d_out;
  float* ws  = (float*)d_ws;   // needs ~76.5 MB

  prep_kernel<<<512, 256, 0, stream>>>(alphas, wconv3, wdil3, ws);
  pre_kernel<<<dim3(B, 8, 2), 256, 0, stream>>>(input0, input1, wpre0, wpre1, ws);

  const float* s0 = ws + S0_OFF;
  const float* s1 = ws + S1_OFF;
  const int wsb = C * HW;       // batch stride of ws-resident states
  const int ob  = OUTC * HW;    // batch stride of d_out-resident states

  // node0: s2 = mix(s0, e0) + mix(s1, e1)
  node_kernel<<<dim3(B, 16), 256, 0, stream>>>(s0, wsb, s1, wsb, ws, 0, out + 0 * C * HW);
  // node1: s3 = mix(s1, e2) + mix(s2, e3)
  node_kernel<<<dim3(B, 16), 256, 0, stream>>>(s1, wsb, out + 0 * C * HW, ob, ws, 2, out + 1 * C * HW);
  // node2: s4 = mix(s2, e4) + mix(s3, e5)
  node_kernel<<<dim3(B, 16), 256, 0, stream>>>(out + 0 * C * HW, ob, out + 1 * C * HW, ob, ws, 4, out + 2 * C * HW);
  // node3: s5 = mix(s3, e6) + mix(s4, e7)
  node_kernel<<<dim3(B, 16), 256, 0, stream>>>(out + 1 * C * HW, ob, out + 2 * C * HW, ob, ws, 6, out + 3 * C * HW);

  skip_kernel<<<(NSKIP / 4 + 255) / 256, 256, 0, stream>>>(skip, out);
}

// Round 6
// 11000.405 us; speedup vs baseline: 2.9656x; 1.0244x over previous
//
#include <hip/hip_runtime.h>
#include <math.h>

// Problem constants
#define B    64
#define C    128
#define H    32
#define W    32
#define HW   1024          // H*W
#define OUTC 640           // 5*C
#define NSKIP (B*C*HW)     // 8388608
#define NW    (8*C*C*9)    // 1179648 per weight array

// ws layout (in floats)
#define ALPHA_OFF 0                    // 40 floats of softmaxed alphas
#define S0_OFF    64
#define S1_OFF    (S0_OFF + NSKIP)
#define W3_OFF    (S1_OFF + NSKIP)     // alpha1-scaled conv3 weights
#define WD3_OFF   (W3_OFF + NW)        // alpha2-scaled dil3 weights
// total = 19,136,576 floats = 76.5 MB of workspace

// ---------------------------------------------------------------------------
// Prep: softmax(alphas) -> ws[0..40); scale w3 by a1, wd3 by a2 into ws.
// ---------------------------------------------------------------------------
__global__ __launch_bounds__(256) void prep_kernel(
    const float* __restrict__ alphas, const float* __restrict__ w3,
    const float* __restrict__ wd3, float* __restrict__ ws) {
  __shared__ float as[40];
  int tid = threadIdx.x;
  if (tid < 8) {
    float v[5];
    float m = -1e30f;
    for (int j = 0; j < 5; j++) { v[j] = alphas[tid * 5 + j]; m = fmaxf(m, v[j]); }
    float s = 0.f;
    for (int j = 0; j < 5; j++) { v[j] = __expf(v[j] - m); s += v[j]; }
    float inv = 1.f / s;
    for (int j = 0; j < 5; j++) as[tid * 5 + j] = v[j] * inv;
  }
  __syncthreads();
  if (blockIdx.x == 0 && tid < 40) ws[ALPHA_OFF + tid] = as[tid];
  int stride = gridDim.x * blockDim.x;
  for (int i = blockIdx.x * blockDim.x + tid; i < 2 * NW; i += stride) {
    if (i < NW) {
      int o = i / (C * C * 9);
      ws[W3_OFF + i] = as[o * 5 + 1] * w3[i];
    } else {
      int j = i - NW;
      int o = j / (C * C * 9);
      ws[WD3_OFF + j] = as[o * 5 + 2] * wd3[j];
    }
  }
}

// ---------------------------------------------------------------------------
// Preprocess 1x1 convs: s0 = in0 * wp0, s1 = in1 * wp1   (NCHW, OIHW)
// ---------------------------------------------------------------------------
__global__ __launch_bounds__(256) void pre_kernel(
    const float* __restrict__ in0, const float* __restrict__ in1,
    const float* __restrict__ wp0, const float* __restrict__ wp1,
    float* __restrict__ ws) {
  int which = blockIdx.z;
  const float* in = which ? in1 : in0;
  const float* wp = which ? wp1 : wp0;
  float* out = ws + (which ? S1_OFF : S0_OFF);
  int b = blockIdx.x;
  int cg = blockIdx.y;            // 8 groups of 16 co
  int t = threadIdx.x;
  int hw0 = t * 4;

  float4 acc[16];
  #pragma unroll
  for (int k = 0; k < 16; k++) acc[k] = make_float4(0.f, 0.f, 0.f, 0.f);

  const float* ip = in + b * (C * HW) + hw0;
  #pragma unroll 4
  for (int ci = 0; ci < C; ci++) {
    float4 x = *(const float4*)(ip + ci * HW);
    #pragma unroll
    for (int k = 0; k < 16; k++) {
      float wv = wp[(cg * 16 + k) * C + ci];   // uniform -> scalar load
      acc[k].x += wv * x.x; acc[k].y += wv * x.y;
      acc[k].z += wv * x.z; acc[k].w += wv * x.w;
    }
  }
  #pragma unroll
  for (int k = 0; k < 16; k++)
    *(float4*)(out + b * (C * HW) + (cg * 16 + k) * HW + hw0) = acc[k];
}

// ---------------------------------------------------------------------------
// Node kernel: s_new = mix(h0, edge o0) + mix(h1, edge o0+1).
// grid (64 b, 16 co-groups), block 256.  Each thread: 1x4 strip for 8 co.
//
// NO LDS, NO BARRIERS: each thread loads its own 5-row x 8-col neighborhood
// per ci directly from global (L1/L2-resident: block footprint = 2 x 4KB
// planes per ci).  Aggregate L1 traffic 10.7 GB/dispatch ~ 273 us at
// 64B/cyc/CU -- under the 492 us FMA floor, on a separate pipe.  Row indices
// are clamped (address-safe) and zero-padding is reproduced with 0/1
// multiplier masks (exact: 0*garbage = 0).  Loads split 2+4+2 floats so no
// address goes below the plane base; reads may run <=2 floats past a plane
// end, always inside the buffer.
// Round-5 lesson: wave-private LDS bands at stride 40 hit 1.4e8 bank-conflict
// cycles (ds_read_b128 at stride==8 mod 32).  Round-4 lesson: keep VGPR<=128.
// ---------------------------------------------------------------------------
__global__ __launch_bounds__(256) void node_kernel(
    const float* __restrict__ h0, int h0_bs,
    const float* __restrict__ h1, int h1_bs,
    const float* __restrict__ ws, int o0,
    float* __restrict__ out) {
  int b = blockIdx.x;
  int cog = blockIdx.y;           // 16 groups of 8 co
  int tid = threadIdx.x;
  int y = tid >> 3;               // 0..31
  int x0 = (tid & 7) * 4;         // 0..28

  // pool/identity alphas for the two edges (uniform scalar loads)
  float a0_0 = ws[ALPHA_OFF + o0 * 5 + 0];
  float a3_0 = ws[ALPHA_OFF + o0 * 5 + 3];
  float a4_0 = ws[ALPHA_OFF + o0 * 5 + 4];
  float a0_1 = ws[ALPHA_OFF + (o0 + 1) * 5 + 0];
  float a3_1 = ws[ALPHA_OFF + (o0 + 1) * 5 + 3];
  float a4_1 = ws[ALPHA_OFF + (o0 + 1) * 5 + 4];

  const float* w3_e0 = ws + W3_OFF  + o0 * (C * C * 9);
  const float* wd_e0 = ws + WD3_OFF + o0 * (C * C * 9);
  const float* w3_e1 = w3_e0 + (C * C * 9);
  const float* wd_e1 = wd_e0 + (C * C * 9);

  const float* base0 = h0 + b * h0_bs;
  const float* base1 = h1 + b * h1_bs;

  // Per-row (r=0..4 -> image row y+r-2) offsets and 0/1 masks.
  // Ra[i] = value at col x0-2+i (zero outside image).
  //   Ra[0..1] from float2 @ offA (col clamped >=0), mask mA (row valid & x0>0)
  //   Ra[2..5] from float4 @ offB (col x0, always valid col), mask mC (row valid)
  //   Ra[6..7] from float2 @ offB+4, mask mH (row valid & x0<28)
  int offA[5], offB[5];
  float mA[5], mC[5], mH[5];
  #pragma unroll
  for (int r = 0; r < 5; r++) {
    int ry = y + r - 2;
    bool rv = (ry >= 0) && (ry < H);
    int ryc = ry < 0 ? 0 : (ry > H - 1 ? H - 1 : ry);
    offB[r] = ryc * W + x0;
    offA[r] = ryc * W + (x0 > 0 ? x0 - 2 : 0);
    mC[r] = rv ? 1.f : 0.f;
    mA[r] = (rv && x0 > 0) ? 1.f : 0.f;
    mH[r] = (rv && x0 < 28) ? 1.f : 0.f;
  }
  bool ru = (y >= 1), rd = (y <= 30);

  float acc[8][4];
  #pragma unroll
  for (int c = 0; c < 8; c++)
    #pragma unroll
    for (int k = 0; k < 4; k++) acc[c][k] = 0.f;

  #pragma unroll 1
  for (int ci = 0; ci < C; ci++) {
    const float* p0 = base0 + ci * HW;   // uniform advance -> s_add
    const float* p1 = base1 + ci * HW;
    int wq = (cog * 8 * C + ci) * 9;     // weight index for c=0 (uniform)
    int cidx = ci - cog * 8;
    bool dopool = (cidx >= 0) & (cidx < 8);
    float cenA[4], cenB[4], s9A[4], s9B[4], mxA[4], mxB[4];

    // --- r=0 (row y-2): dilated ky=0 ---
    {
      float2 a2 = *(const float2*)(p0 + offA[0]);
      float4 a4 = *(const float4*)(p0 + offB[0]);
      float2 ah = *(const float2*)(p0 + offB[0] + 4);
      float2 b2 = *(const float2*)(p1 + offA[0]);
      float4 b4 = *(const float4*)(p1 + offB[0]);
      float2 bh = *(const float2*)(p1 + offB[0] + 4);
      float Ra[8], Rb[8];
      Ra[0] = a2.x * mA[0]; Ra[1] = a2.y * mA[0];
      Ra[2] = a4.x * mC[0]; Ra[3] = a4.y * mC[0]; Ra[4] = a4.z * mC[0]; Ra[5] = a4.w * mC[0];
      Ra[6] = ah.x * mH[0]; Ra[7] = ah.y * mH[0];
      Rb[0] = b2.x * mA[0]; Rb[1] = b2.y * mA[0];
      Rb[2] = b4.x * mC[0]; Rb[3] = b4.y * mC[0]; Rb[4] = b4.z * mC[0]; Rb[5] = b4.w * mC[0];
      Rb[6] = bh.x * mH[0]; Rb[7] = bh.y * mH[0];
      #pragma unroll
      for (int c = 0; c < 8; c++) {
        int wi = wq + c * (C * 9);
        #pragma unroll
        for (int kx = 0; kx < 3; kx++) {
          float wa = wd_e0[wi + kx], wb = wd_e1[wi + kx];
          #pragma unroll
          for (int k = 0; k < 4; k++) {
            acc[c][k] += wa * Ra[k + 2 * kx];
            acc[c][k] += wb * Rb[k + 2 * kx];
          }
        }
      }
    }
    // --- r=1 (row y-1): conv3 ky=0, pool top row ---
    {
      float2 a2 = *(const float2*)(p0 + offA[1]);
      float4 a4 = *(const float4*)(p0 + offB[1]);
      float2 ah = *(const float2*)(p0 + offB[1] + 4);
      float2 b2 = *(const float2*)(p1 + offA[1]);
      float4 b4 = *(const float4*)(p1 + offB[1]);
      float2 bh = *(const float2*)(p1 + offB[1] + 4);
      float Ra[8], Rb[8];
      Ra[0] = a2.x * mA[1]; Ra[1] = a2.y * mA[1];
      Ra[2] = a4.x * mC[1]; Ra[3] = a4.y * mC[1]; Ra[4] = a4.z * mC[1]; Ra[5] = a4.w * mC[1];
      Ra[6] = ah.x * mH[1]; Ra[7] = ah.y * mH[1];
      Rb[0] = b2.x * mA[1]; Rb[1] = b2.y * mA[1];
      Rb[2] = b4.x * mC[1]; Rb[3] = b4.y * mC[1]; Rb[4] = b4.z * mC[1]; Rb[5] = b4.w * mC[1];
      Rb[6] = bh.x * mH[1]; Rb[7] = bh.y * mH[1];
      #pragma unroll
      for (int c = 0; c < 8; c++) {
        int wi = wq + c * (C * 9);
        #pragma unroll
        for (int kx = 0; kx < 3; kx++) {
          float wa = w3_e0[wi + kx], wb = w3_e1[wi + kx];
          #pragma unroll
          for (int k = 0; k < 4; k++) {
            acc[c][k] += wa * Ra[k + kx + 1];
            acc[c][k] += wb * Rb[k + kx + 1];
          }
        }
      }
      if (dopool) {
        #pragma unroll
        for (int k = 0; k < 4; k++) {
          s9A[k] = Ra[k+1] + Ra[k+2] + Ra[k+3];
          s9B[k] = Rb[k+1] + Rb[k+2] + Rb[k+3];
          float ma = -1e30f, mb = -1e30f;
          if (ru) {
            if (x0 + k >= 1)  { ma = fmaxf(ma, Ra[k+1]); mb = fmaxf(mb, Rb[k+1]); }
            ma = fmaxf(ma, Ra[k+2]); mb = fmaxf(mb, Rb[k+2]);
            if (x0 + k <= 30) { ma = fmaxf(ma, Ra[k+3]); mb = fmaxf(mb, Rb[k+3]); }
          }
          mxA[k] = ma; mxB[k] = mb;
        }
      }
    }
    // --- r=2 (row y): dilated ky=1, conv3 ky=1, pool mid + identity ---
    {
      float2 a2 = *(const float2*)(p0 + offA[2]);
      float4 a4 = *(const float4*)(p0 + offB[2]);
      float2 ah = *(const float2*)(p0 + offB[2] + 4);
      float2 b2 = *(const float2*)(p1 + offA[2]);
      float4 b4 = *(const float4*)(p1 + offB[2]);
      float2 bh = *(const float2*)(p1 + offB[2] + 4);
      float Ra[8], Rb[8];
      Ra[0] = a2.x * mA[2]; Ra[1] = a2.y * mA[2];
      Ra[2] = a4.x * mC[2]; Ra[3] = a4.y * mC[2]; Ra[4] = a4.z * mC[2]; Ra[5] = a4.w * mC[2];
      Ra[6] = ah.x * mH[2]; Ra[7] = ah.y * mH[2];
      Rb[0] = b2.x * mA[2]; Rb[1] = b2.y * mA[2];
      Rb[2] = b4.x * mC[2]; Rb[3] = b4.y * mC[2]; Rb[4] = b4.z * mC[2]; Rb[5] = b4.w * mC[2];
      Rb[6] = bh.x * mH[2]; Rb[7] = bh.y * mH[2];
      #pragma unroll
      for (int c = 0; c < 8; c++) {
        int wi = wq + c * (C * 9);
        #pragma unroll
        for (int kx = 0; kx < 3; kx++) {
          float wa = wd_e0[wi + 3 + kx], wb = wd_e1[wi + 3 + kx];
          #pragma unroll
          for (int k = 0; k < 4; k++) {
            acc[c][k] += wa * Ra[k + 2 * kx];
            acc[c][k] += wb * Rb[k + 2 * kx];
          }
        }
        #pragma unroll
        for (int kx = 0; kx < 3; kx++) {
          float wa = w3_e0[wi + 3 + kx], wb = w3_e1[wi + 3 + kx];
          #pragma unroll
          for (int k = 0; k < 4; k++) {
            acc[c][k] += wa * Ra[k + kx + 1];
            acc[c][k] += wb * Rb[k + kx + 1];
          }
        }
      }
      if (dopool) {
        #pragma unroll
        for (int k = 0; k < 4; k++) {
          s9A[k] += Ra[k+1] + Ra[k+2] + Ra[k+3];
          s9B[k] += Rb[k+1] + Rb[k+2] + Rb[k+3];
          cenA[k] = Ra[k+2]; cenB[k] = Rb[k+2];
          float ma = mxA[k], mb = mxB[k];
          if (x0 + k >= 1)  { ma = fmaxf(ma, Ra[k+1]); mb = fmaxf(mb, Rb[k+1]); }
          ma = fmaxf(ma, Ra[k+2]); mb = fmaxf(mb, Rb[k+2]);
          if (x0 + k <= 30) { ma = fmaxf(ma, Ra[k+3]); mb = fmaxf(mb, Rb[k+3]); }
          mxA[k] = ma; mxB[k] = mb;
        }
      }
    }
    // --- r=3 (row y+1): conv3 ky=2, pool bottom row ---
    {
      float2 a2 = *(const float2*)(p0 + offA[3]);
      float4 a4 = *(const float4*)(p0 + offB[3]);
      float2 ah = *(const float2*)(p0 + offB[3] + 4);
      float2 b2 = *(const float2*)(p1 + offA[3]);
      float4 b4 = *(const float4*)(p1 + offB[3]);
      float2 bh = *(const float2*)(p1 + offB[3] + 4);
      float Ra[8], Rb[8];
      Ra[0] = a2.x * mA[3]; Ra[1] = a2.y * mA[3];
      Ra[2] = a4.x * mC[3]; Ra[3] = a4.y * mC[3]; Ra[4] = a4.z * mC[3]; Ra[5] = a4.w * mC[3];
      Ra[6] = ah.x * mH[3]; Ra[7] = ah.y * mH[3];
      Rb[0] = b2.x * mA[3]; Rb[1] = b2.y * mA[3];
      Rb[2] = b4.x * mC[3]; Rb[3] = b4.y * mC[3]; Rb[4] = b4.z * mC[3]; Rb[5] = b4.w * mC[3];
      Rb[6] = bh.x * mH[3]; Rb[7] = bh.y * mH[3];
      #pragma unroll
      for (int c = 0; c < 8; c++) {
        int wi = wq + c * (C * 9);
        #pragma unroll
        for (int kx = 0; kx < 3; kx++) {
          float wa = w3_e0[wi + 6 + kx], wb = w3_e1[wi + 6 + kx];
          #pragma unroll
          for (int k = 0; k < 4; k++) {
            acc[c][k] += wa * Ra[k + kx + 1];
            acc[c][k] += wb * Rb[k + kx + 1];
          }
        }
      }
      if (dopool) {
        #pragma unroll
        for (int k = 0; k < 4; k++) {
          s9A[k] += Ra[k+1] + Ra[k+2] + Ra[k+3];
          s9B[k] += Rb[k+1] + Rb[k+2] + Rb[k+3];
          float ma = mxA[k], mb = mxB[k];
          if (rd) {
            if (x0 + k >= 1)  { ma = fmaxf(ma, Ra[k+1]); mb = fmaxf(mb, Rb[k+1]); }
            ma = fmaxf(ma, Ra[k+2]); mb = fmaxf(mb, Rb[k+2]);
            if (x0 + k <= 30) { ma = fmaxf(ma, Ra[k+3]); mb = fmaxf(mb, Rb[k+3]); }
          }
          mxA[k] = ma; mxB[k] = mb;
        }
      }
    }
    // --- r=4 (row y+2): dilated ky=2 ---
    {
      float2 a2 = *(const float2*)(p0 + offA[4]);
      float4 a4 = *(const float4*)(p0 + offB[4]);
      float2 ah = *(const float2*)(p0 + offB[4] + 4);
      float2 b2 = *(const float2*)(p1 + offA[4]);
      float4 b4 = *(const float4*)(p1 + offB[4]);
      float2 bh = *(const float2*)(p1 + offB[4] + 4);
      float Ra[8], Rb[8];
      Ra[0] = a2.x * mA[4]; Ra[1] = a2.y * mA[4];
      Ra[2] = a4.x * mC[4]; Ra[3] = a4.y * mC[4]; Ra[4] = a4.z * mC[4]; Ra[5] = a4.w * mC[4];
      Ra[6] = ah.x * mH[4]; Ra[7] = ah.y * mH[4];
      Rb[0] = b2.x * mA[4]; Rb[1] = b2.y * mA[4];
      Rb[2] = b4.x * mC[4]; Rb[3] = b4.y * mC[4]; Rb[4] = b4.z * mC[4]; Rb[5] = b4.w * mC[4];
      Rb[6] = bh.x * mH[4]; Rb[7] = bh.y * mH[4];
      #pragma unroll
      for (int c = 0; c < 8; c++) {
        int wi = wq + c * (C * 9);
        #pragma unroll
        for (int kx = 0; kx < 3; kx++) {
          float wa = wd_e0[wi + 6 + kx], wb = wd_e1[wi + 6 + kx];
          #pragma unroll
          for (int k = 0; k < 4; k++) {
            acc[c][k] += wa * Ra[k + 2 * kx];
            acc[c][k] += wb * Rb[k + 2 * kx];
          }
        }
      }
    }
    // --- identity / avg / max contribution ---
    if (dopool) {
      #pragma unroll
      for (int k = 0; k < 4; k++) {
        acc[cidx][k] += a0_0 * cenA[k] + a3_0 * (s9A[k] * (1.f / 9.f)) + a4_0 * mxA[k];
        acc[cidx][k] += a0_1 * cenB[k] + a3_1 * (s9B[k] * (1.f / 9.f)) + a4_1 * mxB[k];
      }
    }
  }

  // ---- write out (channel slot already folded into `out`) ----
  #pragma unroll
  for (int c = 0; c < 8; c++) {
    float* op = out + b * (OUTC * HW) + (cog * 8 + c) * HW + y * W + x0;
    *(float4*)op = make_float4(acc[c][0], acc[c][1], acc[c][2], acc[c][3]);
  }
}

// ---------------------------------------------------------------------------
// skip_input -> out channels [512,640) and second tuple output
// ---------------------------------------------------------------------------
__global__ __launch_bounds__(256) void skip_kernel(
    const float* __restrict__ skip, float* __restrict__ dout) {
  int i = blockIdx.x * 256 + threadIdx.x;     // over NSKIP/4 float4s
  if (i < NSKIP / 4) {
    float4 v = ((const float4*)skip)[i];
    int e = i * 4;
    int b = e >> 17;                 // / (C*HW)
    int rem = e & (C * HW - 1);
    *(float4*)(dout + b * (OUTC * HW) + 512 * HW + rem) = v;
    *(float4*)(dout + B * (OUTC * HW) + e) = v;
  }
}

// ---------------------------------------------------------------------------
extern "C" void kernel_launch(void* const* d_in, const int* in_sizes, int n_in,
                              void* d_out, int out_size, void* d_ws, size_t ws_size,
                              hipStream_t stream) {
  const float* input0 = (const float*)d_in[0];
  const float* input1 = (const float*)d_in[1];
  const float* skip   = (const float*)d_in[2];
  const float* wpre0  = (const float*)d_in[3];
  const float* wpre1  = (const float*)d_in[4];
  const float* wconv3 = (const float*)d_in[5];
  const float* wdil3  = (const float*)d_in[6];
  const float* alphas = (const float*)d_in[7];
  float* out = (float*)d_out;
  float* ws  = (float*)d_ws;   // needs ~76.5 MB

  prep_kernel<<<512, 256, 0, stream>>>(alphas, wconv3, wdil3, ws);
  pre_kernel<<<dim3(B, 8, 2), 256, 0, stream>>>(input0, input1, wpre0, wpre1, ws);

  const float* s0 = ws + S0_OFF;
  const float* s1 = ws + S1_OFF;
  const int wsb = C * HW;       // batch stride of ws-resident states
  const int ob  = OUTC * HW;    // batch stride of d_out-resident states

  // node0: s2 = mix(s0, e0) + mix(s1, e1)
  node_kernel<<<dim3(B, 16), 256, 0, stream>>>(s0, wsb, s1, wsb, ws, 0, out + 0 * C * HW);
  // node1: s3 = mix(s1, e2) + mix(s2, e3)
  node_kernel<<<dim3(B, 16), 256, 0, stream>>>(s1, wsb, out + 0 * C * HW, ob, ws, 2, out + 1 * C * HW);
  // node2: s4 = mix(s2, e4) + mix(s3, e5)
  node_kernel<<<dim3(B, 16), 256, 0, stream>>>(out + 0 * C * HW, ob, out + 1 * C * HW, ob, ws, 4, out + 2 * C * HW);
  // node3: s5 = mix(s3, e6) + mix(s4, e7)
  node_kernel<<<dim3(B, 16), 256, 0, stream>>>(out + 1 * C * HW, ob, out + 2 * C * HW, ob, ws, 6, out + 3 * C * HW);

  skip_kernel<<<(NSKIP / 4 + 255) / 256, 256, 0, stream>>>(skip, out);
}